// Round 4
// baseline (252.360 us; speedup 1.0000x reference)
//
#include <hip/hip_runtime.h>
#include <hip/hip_bf16.h>

// Problem constants
#define H_ 128
#define W_ 128
#define HW 16384          // H*W
#define CIN 64
#define COUT 128
#define KK9 9
#define BATCH 8
#define NPIX (BATCH * HW) // 131072
#define KDIM 576          // CIN*KK9

typedef short bf16x8 __attribute__((ext_vector_type(8)));
typedef float f32x4  __attribute__((ext_vector_type(4)));
typedef unsigned short ushort_t;

union U4B { uint4 u; bf16x8 v; };

__device__ __forceinline__ float us2f(unsigned short u) {
    unsigned int v = ((unsigned int)u) << 16;
    float f;
    __builtin_memcpy(&f, &v, 4);
    return f;
}
__device__ __forceinline__ float lo_f(unsigned int w) {
    unsigned int v = w << 16;
    float f;
    __builtin_memcpy(&f, &v, 4);
    return f;
}
__device__ __forceinline__ float hi_f(unsigned int w) {
    unsigned int v = w & 0xffff0000u;
    float f;
    __builtin_memcpy(&f, &v, 4);
    return f;
}
__device__ __forceinline__ unsigned short f2us_bf(float f) {
    __hip_bfloat16 h = __float2bfloat16(f);
    unsigned short u;
    __builtin_memcpy(&u, &h, 2);
    return u;
}
__device__ __forceinline__ unsigned int pack2(float a, float b) {
    return (unsigned int)f2us_bf(a) | ((unsigned int)f2us_bf(b) << 16);
}

template <bool F32>
__device__ __forceinline__ float ld_in(const void* p, long i) {
    if (F32) return ((const float*)p)[i];
    return us2f(((const unsigned short*)p)[i]);
}

// ---------------------------------------------------------------------------
// detect_zero: dtype probe (1 wave, vector loads, ballot) + zero gstat.
// ---------------------------------------------------------------------------
__global__ void detect_zero(const uint4* __restrict__ xr4,
                            float* __restrict__ flag,
                            float* __restrict__ gstat) {
    int t = threadIdx.x;   // 256
#pragma unroll
    for (int i = 0; i < 16; ++i) gstat[i * 256 + t] = 0.0f;
    if (t < 64) {
        uint4 v = xr4[t];
        unsigned int w[4] = {v.x, v.y, v.z, v.w};
        int big = 0;
#pragma unroll
        for (int q = 0; q < 4; ++q) {
            big += (((w[q] >> 7)  & 0xFF) >= 0xC0);
            big += (((w[q] >> 23) & 0xFF) >= 0xC0);
        }
        unsigned long long m = __ballot(big > 0);
        if (t == 0) flag[0] = m ? 1.0f : 0.0f;
    }
}

// ---------------------------------------------------------------------------
// prep_weights: weights in MFMA-fragment-linear order. Single kernel,
// internal wave-uniform branch on flag.
// ---------------------------------------------------------------------------
template <bool F32>
__device__ __forceinline__ void prep_body(const void* offw, const void* offb,
                                          const void* maskw, const void* maskb,
                                          const void* convw,
                                          ushort_t* wTs, ushort_t* wcats,
                                          float* bias, int i) {
    if (i < 73728) {
        int j = i & 7, lane = (i >> 3) & 63, n = (i >> 9) & 7, ks = i >> 12;
        int co = n * 16 + (lane & 15);
        int k  = ks * 32 + ((lane >> 4) << 3) + j;
        int kk = k >> 6, ci = k & 63;
        wTs[i] = f2us_bf(ld_in<F32>(convw, (long)co * KDIM + ci * 9 + kk));
    } else if (i < 73728 + 18432) {
        int i2 = i - 73728;
        int j = i2 & 7, lane = (i2 >> 3) & 63, n = (i2 >> 9) & 1, ks = i2 >> 10;
        int co2 = n * 16 + (lane & 15);
        int k   = ks * 32 + ((lane >> 4) << 3) + j;
        int kk = k >> 6, ci = k & 63;
        float v = 0.0f;
        if (co2 < 18)      v = ld_in<F32>(offw,  (long)co2 * KDIM + ci * 9 + kk);
        else if (co2 < 27) v = ld_in<F32>(maskw, (long)(co2 - 18) * KDIM + ci * 9 + kk);
        wcats[i2] = f2us_bf(v);
    } else if (i < 73728 + 18432 + 32) {
        int j = i - 73728 - 18432;
        float v = 0.0f;
        if (j < 18)      v = ld_in<F32>(offb, j);
        else if (j < 27) v = ld_in<F32>(maskb, j - 18);
        bias[j] = v;
    }
}

__global__ void prep_weights(const void* __restrict__ offw,
                             const void* __restrict__ offb,
                             const void* __restrict__ maskw,
                             const void* __restrict__ maskb,
                             const void* __restrict__ convw,
                             const float* __restrict__ flag,
                             ushort_t* __restrict__ wTs,
                             ushort_t* __restrict__ wcats,
                             float* __restrict__ bias) {
    int i = blockIdx.x * 256 + threadIdx.x;
    if (flag[0] != 0.0f)
        prep_body<true>(offw, offb, maskw, maskb, convw, wTs, wcats, bias, i);
    else
        prep_body<false>(offw, offb, maskw, maskb, convw, wTs, wcats, bias, i);
}

// ---------------------------------------------------------------------------
// transpose_x: raw x NCHW -> NHWC bf16. Single kernel, internal flag branch.
// ---------------------------------------------------------------------------
template <bool F32>
__device__ __forceinline__ void transpose_body(const void* x, ushort_t* xnb) {
    __shared__ float tile[CIN][64 + 1];
    int blk  = blockIdx.x;
    int b    = blk >> 8;
    int pix0 = (blk & 255) * 64;
    int t    = threadIdx.x;
    int lane = t & 63;
    int grp  = t >> 6;
#pragma unroll
    for (int r = 0; r < 16; ++r) {
        int ci = r * 4 + grp;
        tile[ci][lane] = ld_in<F32>(x, (long)(b * CIN + ci) * HW + pix0 + lane);
    }
    __syncthreads();
#pragma unroll
    for (int r = 0; r < 16; ++r) {
        int px = r * 4 + grp;
        xnb[(size_t)(b * HW + pix0 + px) * CIN + lane] = f2us_bf(tile[lane][px]);
    }
}

__global__ __launch_bounds__(256) void transpose_x(const void* __restrict__ x,
                                                   const float* __restrict__ flag,
                                                   ushort_t* __restrict__ xnb) {
    if (flag[0] != 0.0f) transpose_body<true>(x, xnb);
    else                 transpose_body<false>(x, xnb);
}

// ---------------------------------------------------------------------------
// conv_mfma: implicit-GEMM 3x3 conv -> 27 ch. 1024 thr / 256 px / 16 waves.
// XCD-chunked block swizzle (XCD k == batch k).
// ---------------------------------------------------------------------------
__global__ __launch_bounds__(1024, 4) void conv_mfma(
        const ushort_t* __restrict__ xnb,
        const ushort_t* __restrict__ wcats,
        const float* __restrict__ bias,
        float* __restrict__ off2,
        float* __restrict__ mask_ws) {
    __shared__ uint4 ldsB4[2304];    // 36,864 B

    int t    = threadIdx.x;
    int bid  = blockIdx.x;
    int sbid = (bid & 7) * 64 + (bid >> 3);   // 512 = 8 XCDs x 64, bijective
    int pix0 = sbid * 256;
    int b    = pix0 >> 14;
    int rem0 = pix0 & 16383;

    const uint4* ws4 = (const uint4*)wcats;
#pragma unroll
    for (int i = t; i < 2304; i += 1024) ldsB4[i] = ws4[i];

    int wave = t >> 6, lane = t & 63, mrow = lane & 15, quad = lane >> 4;
    int px_l = wave * 16 + mrow;
    int remp = rem0 + px_l;
    int yp = remp >> 7, xp = remp & 127;
    const ushort_t* xb = xnb + (size_t)b * HW * CIN + quad * 8;

    // preload all 9 taps (loads all independent)
    uint4 af0[9], af1[9];
#pragma unroll
    for (int kk = 0; kk < 9; ++kk) {
        int yy = yp + kk / 3 - 1;
        int xq = xp + kk % 3 - 1;
        bool ok = (yy >= 0) && (yy < H_) && (xq >= 0) && (xq < W_);
        const ushort_t* src = xb + (size_t)(yy * W_ + xq) * CIN;
        af0[kk] = ok ? *(const uint4*)src        : make_uint4(0, 0, 0, 0);
        af1[kk] = ok ? *(const uint4*)(src + 32) : make_uint4(0, 0, 0, 0);
    }
    __syncthreads();

    f32x4 acc[2];
    acc[0] = (f32x4){0.f, 0.f, 0.f, 0.f};
    acc[1] = (f32x4){0.f, 0.f, 0.f, 0.f};
    const ushort_t* ldsB = (const ushort_t*)ldsB4;
#pragma unroll
    for (int kk = 0; kk < 9; ++kk) {
#pragma unroll
        for (int half = 0; half < 2; ++half) {
            int ks = kk * 2 + half;
            U4B a; a.u = half ? af1[kk] : af0[kk];
#pragma unroll
            for (int n = 0; n < 2; ++n) {
                bf16x8 bf = *(const bf16x8*)(ldsB + ((ks * 2 + n) * 64 + lane) * 8);
                acc[n] = __builtin_amdgcn_mfma_f32_16x16x32_bf16(a.v, bf, acc[n], 0, 0, 0);
            }
        }
    }

    // epilogue
#pragma unroll
    for (int n = 0; n < 2; ++n) {
        int co2 = n * 16 + mrow;
        if (co2 >= 27) continue;
        float bs = bias[co2];
#pragma unroll
        for (int r = 0; r < 4; ++r) {
            int px = wave * 16 + quad * 4 + r;
            float v = acc[n][r] + bs;
            if (co2 < 18) {
                off2[((size_t)(b * 9 + (co2 >> 1)) * HW + rem0 + px) * 2 + (co2 & 1)] = v;
            } else {
                mask_ws[(size_t)(b * 9 + (co2 - 18)) * HW + rem0 + px] =
                    1.0f / (1.0f + __expf(-v));
            }
        }
    }
}

// ---------------------------------------------------------------------------
// deform helpers.
// compute_tap: element offsets + mask-folded bilinear weights.
// issue_half: 4 corner loads of one 8-channel half (4 uint4 = 16 VGPR).
// interp_pack: interp 4 words + pack -> one A-fragment (16 B).
// ---------------------------------------------------------------------------
__device__ __forceinline__ void compute_tap(int yp_t, int xp_t,
                                            float oy, float ox, float mk,
                                            int* ofs, float* wg) {
    float py  = (float)yp_t + oy;
    float pxf = (float)xp_t + ox;
    float y0f = floorf(py), x0f = floorf(pxf);
    int yi = (int)y0f, xi = (int)x0f;
    float wy1 = py - y0f, wx1 = pxf - x0f;
    float wy0 = 1.0f - wy1, wx0 = 1.0f - wx1;
    int ya  = min(max(yi, 0), H_ - 1);
    int yb  = min(max(yi + 1, 0), H_ - 1);
    int xa  = min(max(xi, 0), W_ - 1);
    int xb2 = min(max(xi + 1, 0), W_ - 1);
    bool vy0 = (yi >= 0) & (yi < H_);
    bool vy1 = (yi >= -1) & (yi < H_ - 1);
    bool vx0 = (xi >= 0) & (xi < W_);
    bool vx1 = (xi >= -1) & (xi < W_ - 1);
    float m0 = mk * wy0, m1 = mk * wy1;
    wg[0] = (vy0 & vx0) ? m0 * wx0 : 0.0f;
    wg[1] = (vy0 & vx1) ? m0 * wx1 : 0.0f;
    wg[2] = (vy1 & vx0) ? m1 * wx0 : 0.0f;
    wg[3] = (vy1 & vx1) ? m1 * wx1 : 0.0f;
    int ra = ya << 13, rb = yb << 13;   // y * W_ * CIN
    int ca = xa << 6,  cb_ = xb2 << 6;  // x * CIN
    ofs[0] = ra + ca;  ofs[1] = ra + cb_;
    ofs[2] = rb + ca;  ofs[3] = rb + cb_;
}

__device__ __forceinline__ void issue_half(const ushort_t* __restrict__ xb,
                                           const int* ofs, int hoff, uint4* cb) {
#pragma unroll
    for (int c = 0; c < 4; ++c)
        cb[c] = *(const uint4*)(xb + ofs[c] + hoff);
}

__device__ __forceinline__ uint4 interp_pack(const uint4* cb, const float* wg) {
    float2 v2[4];
#pragma unroll
    for (int j = 0; j < 4; ++j) v2[j] = make_float2(0.f, 0.f);
#pragma unroll
    for (int c = 0; c < 4; ++c) {
        float w = wg[c];
        unsigned int ww[4] = {cb[c].x, cb[c].y, cb[c].z, cb[c].w};
#pragma unroll
        for (int j = 0; j < 4; ++j) {
            v2[j].x = fmaf(w, lo_f(ww[j]), v2[j].x);
            v2[j].y = fmaf(w, hi_f(ww[j]), v2[j].y);
        }
    }
    return make_uint4(pack2(v2[0].x, v2[0].y), pack2(v2[1].x, v2[1].y),
                      pack2(v2[2].x, v2[2].y), pack2(v2[3].x, v2[3].y));
}

// ---------------------------------------------------------------------------
// deform_mfma: producer/consumer wave specialization.
// 1024 thr / 128 px / 16 waves per block; 1024 blocks (XCD-chunked: XCD k ==
// batch k). Waves 0..7 = PRODUCERS: gather 4 corners (3-deep in-register
// ring, no accumulator -> regs free for lookahead), bilinear-interp + pack,
// ds_write A-fragment to a double-buffered LDS tile. Waves 8..15 =
// CONSUMERS: ds_read A + B, 8 MFMAs per half-step; never touch global
// memory in the loop. B (W^T) is K-split: 9 K-slots (72 KB) staged, consumed
// over 9 half-steps, restaged for the last 9. LDS = 72K B + 16K A = 88 KB.
// The two roles run separate top-level loops with MATCHING barrier counts
// (20 each) -- s_barrier pairs across uniform divergence; consumer acc never
// overlaps producer register peak. All ring/parity indices are constexpr
// (explicit macro steps) -- no runtime-indexed arrays (scratch hazard).
// ---------------------------------------------------------------------------
__global__ __launch_bounds__(1024, 4) void deform_mfma(
        const ushort_t* __restrict__ xnb,
        const float* __restrict__ off2,
        const float* __restrict__ mask_ws,
        const ushort_t* __restrict__ wTs,
        ushort_t* __restrict__ prebn,
        float* __restrict__ gstat) {
    __shared__ uint4 ldsB4[4608];    // 73,728 B : 9 K-slots of B
    __shared__ uint4 ldsA4[1024];    // 16,384 B : A ring-2 (8 groups x 64 x 16B)

    int t    = threadIdx.x;
    int bid  = blockIdx.x;
    int sbid = (bid & 7) * 128 + (bid >> 3);  // 1024 = 8 XCDs x 128, bijective
    int pix0 = sbid * 128;
    int b    = pix0 >> 14;
    int rem0 = pix0 & 16383;

    const uint4* ws4 = (const uint4*)wTs;
    for (int i = t; i < 4608; i += 1024) ldsB4[i] = ws4[i];   // B half 0

    int wave = t >> 6, lane = t & 63, mrow = lane & 15, quad = lane >> 4;
    int grp  = wave & 7;                 // pixel group 0..7 (producer==consumer pairing)
    int px_l = grp * 16 + mrow;
    int remp = rem0 + px_l;
    int yp = remp >> 7, xp = remp & 127;
    const ushort_t* xb = xnb + (size_t)b * HW * CIN + quad * 8;
    int obase = b * 9 * HW + remp;       // fits in int

    if (wave < 8) {
        // =================== PRODUCER PATH ===================
        uint4 G0[4], G1[4], G2[4];
        int   ofsE[4], ofsO[4];
        float wgE[4], wgO[4];
        float2 oE, oO;
        float  mkE, mkO;

#define GSEL(c) ((c) == 0 ? G0 : (c) == 1 ? G1 : G2)

        // pre-fill: taps 0,1; gathers for hs 0,1,2; interp hs0 -> A[0]
        oE = *(const float2*)(off2 + (size_t)obase * 2);          mkE = mask_ws[obase];
        oO = *(const float2*)(off2 + (size_t)(obase + HW) * 2);   mkO = mask_ws[obase + HW];
        compute_tap(yp - 1, xp - 1, oE.x, oE.y, mkE, ofsE, wgE);  // tap0
        issue_half(xb, ofsE, 0,  G0);
        issue_half(xb, ofsE, 32, G1);
        oE = *(const float2*)(off2 + (size_t)(obase + 2 * HW) * 2); mkE = mask_ws[obase + 2 * HW];
        compute_tap(yp - 1, xp, oO.x, oO.y, mkO, ofsO, wgO);      // tap1 (ty0,tx1)
        issue_half(xb, ofsO, 0, G2);
        oO = *(const float2*)(off2 + (size_t)(obase + 3 * HW) * 2); mkO = mask_ws[obase + 3 * HW];
        ldsA4[grp * 64 + lane] = interp_pack(G0, wgE);            // A[0] <- hs0
        __syncthreads();                                          // SYNC 1

#define PSTEP(HS) do {                                                        \
    constexpr int ihs = (HS) + 3;                                             \
    if constexpr (ihs < 18) {                                                 \
        constexpr int T = ihs >> 1;                                           \
        if constexpr ((ihs & 1) == 0) {                                       \
            if constexpr (T & 1) {                                            \
                compute_tap(yp + T / 3 - 1, xp + T % 3 - 1,                   \
                            oO.x, oO.y, mkO, ofsO, wgO);                      \
                issue_half(xb, ofsO, 0, GSEL(ihs % 3));                       \
                if constexpr (T + 2 <= 8) {                                   \
                    oO = *(const float2*)(off2 + (size_t)(obase + (T + 2) * HW) * 2); \
                    mkO = mask_ws[obase + (T + 2) * HW];                      \
                }                                                             \
            } else {                                                          \
                compute_tap(yp + T / 3 - 1, xp + T % 3 - 1,                   \
                            oE.x, oE.y, mkE, ofsE, wgE);                      \
                issue_half(xb, ofsE, 0, GSEL(ihs % 3));                       \
                if constexpr (T + 2 <= 8) {                                   \
                    oE = *(const float2*)(off2 + (size_t)(obase + (T + 2) * HW) * 2); \
                    mkE = mask_ws[obase + (T + 2) * HW];                      \
                }                                                             \
            }                                                                 \
        } else {                                                              \
            if constexpr (T & 1) issue_half(xb, ofsO, 32, GSEL(ihs % 3));     \
            else                 issue_half(xb, ofsE, 32, GSEL(ihs % 3));     \
        }                                                                     \
    }                                                                         \
    __builtin_amdgcn_sched_barrier(0);  /* issues stay ahead of interp */     \
    constexpr int jhs = (HS) + 1;                                             \
    if constexpr (jhs < 18) {                                                 \
        uint4 av = interp_pack(GSEL(jhs % 3),                                 \
                               ((jhs >> 1) & 1) ? wgO : wgE);                 \
        ldsA4[(jhs & 1) * 512 + grp * 64 + lane] = av;                        \
    }                                                                         \
    __syncthreads();                                                          \
} while (0)

        PSTEP(0);  PSTEP(1);  PSTEP(2);  PSTEP(3);  PSTEP(4);
        PSTEP(5);  PSTEP(6);  PSTEP(7);  PSTEP(8);                 // SYNC 2..10
        for (int i = t; i < 4608; i += 1024) ldsB4[i] = ws4[4608 + i]; // B half 1
        __syncthreads();                                           // SYNC 11
        PSTEP(9);  PSTEP(10); PSTEP(11); PSTEP(12); PSTEP(13);
        PSTEP(14); PSTEP(15); PSTEP(16); PSTEP(17);                // SYNC 12..20
#undef PSTEP
#undef GSEL
    } else {
        // =================== CONSUMER PATH ===================
        f32x4 acc[8];
#pragma unroll
        for (int n = 0; n < 8; ++n) acc[n] = (f32x4){0.f, 0.f, 0.f, 0.f};
        const ushort_t* ldsB = (const ushort_t*)ldsB4;

        __syncthreads();                                           // SYNC 1

#define CSTEP(HS, SLOT) do {                                                  \
    U4B a; a.u = ldsA4[((HS) & 1) * 512 + grp * 64 + lane];                   \
    __builtin_amdgcn_s_setprio(1);                                            \
    _Pragma("unroll")                                                         \
    for (int n = 0; n < 8; ++n) {                                             \
        bf16x8 bf = *(const bf16x8*)(ldsB + (((SLOT) * 8 + n) * 64 + lane) * 8); \
        acc[n] = __builtin_amdgcn_mfma_f32_16x16x32_bf16(a.v, bf, acc[n], 0, 0, 0); \
    }                                                                         \
    __builtin_amdgcn_s_setprio(0);                                            \
    __syncthreads();                                                          \
} while (0)

        CSTEP(0, 0);  CSTEP(1, 1);  CSTEP(2, 2);  CSTEP(3, 3);  CSTEP(4, 4);
        CSTEP(5, 5);  CSTEP(6, 6);  CSTEP(7, 7);  CSTEP(8, 8);    // SYNC 2..10
        for (int i = t; i < 4608; i += 1024) ldsB4[i] = ws4[4608 + i]; // B half 1
        __syncthreads();                                           // SYNC 11
        CSTEP(9, 0);  CSTEP(10, 1); CSTEP(11, 2); CSTEP(12, 3); CSTEP(13, 4);
        CSTEP(14, 5); CSTEP(15, 6); CSTEP(16, 7); CSTEP(17, 8);   // SYNC 12..20
#undef CSTEP

        // ---- epilogue: bf16 NHWC store + BN stats (shuffle + global atomics)
#pragma unroll
        for (int n = 0; n < 8; ++n) {
            int co = n * 16 + mrow;
            float s = 0.f, ss = 0.f;
#pragma unroll
            for (int r = 0; r < 4; ++r) {
                int pg = pix0 + grp * 16 + quad * 4 + r;
                float v = acc[n][r];
                prebn[(size_t)pg * COUT + co] = f2us_bf(v);
                s += v;
                ss += v * v;
            }
            s  += __shfl_xor(s, 16, 64);
            s  += __shfl_xor(s, 32, 64);
            ss += __shfl_xor(ss, 16, 64);
            ss += __shfl_xor(ss, 32, 64);
            if (quad == 0) {
                atomicAdd(&gstat[(bid & 15) * 256 + co], s);
                atomicAdd(&gstat[(bid & 15) * 256 + 128 + co], ss);
            }
        }
    }
}

// ---------------------------------------------------------------------------
// bn_apply_t: derive mean/rstd from gstat per block (cheap), then read pre-BN
// bf16 NHWC, normalize+ReLU, write f32 NCHW d_out via LDS transpose tile.
// ---------------------------------------------------------------------------
__global__ __launch_bounds__(256) void bn_apply_t(const ushort_t* __restrict__ prebn,
                                                  const float* __restrict__ gstat,
                                                  float* __restrict__ out) {
    __shared__ float tile[128 * 65];
    __shared__ float mvs[256];
    int t = threadIdx.x;
    if (t < 128) {
        float s = 0.f, ss = 0.f;
#pragma unroll
        for (int part = 0; part < 16; ++part) {
            s  += gstat[part * 256 + t];
            ss += gstat[part * 256 + 128 + t];
        }
        const float invN = 1.0f / (float)NPIX;
        float mean = s * invN;
        float var  = ss * invN - mean * mean;
        if (!isfinite(mean)) mean = 0.0f;
        float r = rsqrtf(fmaxf(var, 0.0f) + 1e-5f);
        if (!isfinite(r)) r = 1.0f;
        mvs[t]       = mean;
        mvs[128 + t] = r;
    }
    __syncthreads();
    int pix0 = blockIdx.x * 64;
    int b    = pix0 >> 14;
    int rem0 = pix0 & 16383;
    const ushort_t* src = prebn + (size_t)pix0 * COUT;
#pragma unroll
    for (int r = 0; r < 32; ++r) {
        int i = r * 256 + t;
        int p = i >> 7, c = i & 127;
        float v = us2f(src[i]);
        v = fmaxf((v - mvs[c]) * mvs[128 + c], 0.0f);
        tile[c * 65 + p] = v;
    }
    __syncthreads();
#pragma unroll
    for (int r = 0; r < 32; ++r) {
        int i = r * 256 + t;
        int c2 = i >> 6, p2 = i & 63;
        out[(size_t)(b * COUT + c2) * HW + rem0 + p2] = tile[c2 * 65 + p2];
    }
}

// ---------------------------------------------------------------------------
extern "C" void kernel_launch(void* const* d_in, const int* in_sizes, int n_in,
                              void* d_out, int out_size, void* d_ws, size_t ws_size,
                              hipStream_t stream) {
    (void)in_sizes; (void)n_in; (void)out_size; (void)ws_size;
    const void* x     = d_in[0];
    const void* offw  = d_in[1];
    const void* offb  = d_in[2];
    const void* maskw = d_in[3];
    const void* maskb = d_in[4];
    const void* convw = d_in[5];

    float* ws       = (float*)d_ws;
    float* off2     = ws;                      // 2,359,296 f32 (y,x interleaved)
    float* mask_ws  = off2 + 2359296;          // 1,179,648 f32
    float* bias     = mask_ws + 1179648;       //        32 f32
    float* gstat    = bias + 32;               //     4,096 f32
    float* flag     = gstat + 4096;            //        16 f32
    ushort_t* wTs   = (ushort_t*)(flag + 16);  //    73,728 bf16 (frag-linear)
    ushort_t* wcats = wTs + 73728;             //    18,432 bf16 (frag-linear)
    ushort_t* xnb   = wcats + 18432;           // 8,388,608 bf16 (NHWC x)
    ushort_t* prebn = xnb + 8388608;           // 16,777,216 bf16 (NHWC pre-BN)
    float* out      = (float*)d_out;

    detect_zero<<<1, 256, 0, stream>>>((const uint4*)x, flag, gstat);
    prep_weights<<<361, 256, 0, stream>>>(offw, offb, maskw, maskb, convw, flag, wTs, wcats, bias);
    transpose_x<<<2048, 256, 0, stream>>>(x, flag, xnb);
    conv_mfma<<<512, 1024, 0, stream>>>(xnb, wcats, bias, off2, mask_ws);
    deform_mfma<<<1024, 1024, 0, stream>>>(xnb, off2, mask_ws, wTs, prebn, gstat);
    bn_apply_t<<<2048, 256, 0, stream>>>(prebn, gstat, out);
}

// Round 5
// 207.450 us; speedup vs baseline: 1.2165x; 1.2165x over previous
//
#include <hip/hip_runtime.h>
#include <hip/hip_bf16.h>

// Problem constants
#define H_ 128
#define W_ 128
#define HW 16384          // H*W
#define CIN 64
#define COUT 128
#define KK9 9
#define BATCH 8
#define NPIX (BATCH * HW) // 131072
#define KDIM 576          // CIN*KK9

typedef short bf16x8 __attribute__((ext_vector_type(8)));
typedef float f32x4  __attribute__((ext_vector_type(4)));
typedef unsigned short ushort_t;

union U4B { uint4 u; bf16x8 v; };

__device__ __forceinline__ float us2f(unsigned short u) {
    unsigned int v = ((unsigned int)u) << 16;
    float f;
    __builtin_memcpy(&f, &v, 4);
    return f;
}
__device__ __forceinline__ float lo_f(unsigned int w) {
    unsigned int v = w << 16;
    float f;
    __builtin_memcpy(&f, &v, 4);
    return f;
}
__device__ __forceinline__ float hi_f(unsigned int w) {
    unsigned int v = w & 0xffff0000u;
    float f;
    __builtin_memcpy(&f, &v, 4);
    return f;
}
__device__ __forceinline__ unsigned short f2us_bf(float f) {
    __hip_bfloat16 h = __float2bfloat16(f);
    unsigned short u;
    __builtin_memcpy(&u, &h, 2);
    return u;
}
__device__ __forceinline__ unsigned int pack2(float a, float b) {
    return (unsigned int)f2us_bf(a) | ((unsigned int)f2us_bf(b) << 16);
}

template <bool F32>
__device__ __forceinline__ float ld_in(const void* p, long i) {
    if (F32) return ((const float*)p)[i];
    return us2f(((const unsigned short*)p)[i]);
}

// ---------------------------------------------------------------------------
// detect_zero: dtype probe (1 wave, vector loads, ballot) + zero gstat.
// ---------------------------------------------------------------------------
__global__ void detect_zero(const uint4* __restrict__ xr4,
                            float* __restrict__ flag,
                            float* __restrict__ gstat) {
    int t = threadIdx.x;   // 256
#pragma unroll
    for (int i = 0; i < 16; ++i) gstat[i * 256 + t] = 0.0f;
    if (t < 64) {
        uint4 v = xr4[t];
        unsigned int w[4] = {v.x, v.y, v.z, v.w};
        int big = 0;
#pragma unroll
        for (int q = 0; q < 4; ++q) {
            big += (((w[q] >> 7)  & 0xFF) >= 0xC0);
            big += (((w[q] >> 23) & 0xFF) >= 0xC0);
        }
        unsigned long long m = __ballot(big > 0);
        if (t == 0) flag[0] = m ? 1.0f : 0.0f;
    }
}

// ---------------------------------------------------------------------------
// prep_weights: weights in MFMA-fragment-linear order.
// ---------------------------------------------------------------------------
template <bool F32>
__device__ __forceinline__ void prep_body(const void* offw, const void* offb,
                                          const void* maskw, const void* maskb,
                                          const void* convw,
                                          ushort_t* wTs, ushort_t* wcats,
                                          float* bias, int i) {
    if (i < 73728) {
        int j = i & 7, lane = (i >> 3) & 63, n = (i >> 9) & 7, ks = i >> 12;
        int co = n * 16 + (lane & 15);
        int k  = ks * 32 + ((lane >> 4) << 3) + j;
        int kk = k >> 6, ci = k & 63;
        wTs[i] = f2us_bf(ld_in<F32>(convw, (long)co * KDIM + ci * 9 + kk));
    } else if (i < 73728 + 18432) {
        int i2 = i - 73728;
        int j = i2 & 7, lane = (i2 >> 3) & 63, n = (i2 >> 9) & 1, ks = i2 >> 10;
        int co2 = n * 16 + (lane & 15);
        int k   = ks * 32 + ((lane >> 4) << 3) + j;
        int kk = k >> 6, ci = k & 63;
        float v = 0.0f;
        if (co2 < 18)      v = ld_in<F32>(offw,  (long)co2 * KDIM + ci * 9 + kk);
        else if (co2 < 27) v = ld_in<F32>(maskw, (long)(co2 - 18) * KDIM + ci * 9 + kk);
        wcats[i2] = f2us_bf(v);
    } else if (i < 73728 + 18432 + 32) {
        int j = i - 73728 - 18432;
        float v = 0.0f;
        if (j < 18)      v = ld_in<F32>(offb, j);
        else if (j < 27) v = ld_in<F32>(maskb, j - 18);
        bias[j] = v;
    }
}

__global__ void prep_weights(const void* __restrict__ offw,
                             const void* __restrict__ offb,
                             const void* __restrict__ maskw,
                             const void* __restrict__ maskb,
                             const void* __restrict__ convw,
                             const float* __restrict__ flag,
                             ushort_t* __restrict__ wTs,
                             ushort_t* __restrict__ wcats,
                             float* __restrict__ bias) {
    int i = blockIdx.x * 256 + threadIdx.x;
    if (flag[0] != 0.0f)
        prep_body<true>(offw, offb, maskw, maskb, convw, wTs, wcats, bias, i);
    else
        prep_body<false>(offw, offb, maskw, maskb, convw, wTs, wcats, bias, i);
}

// ---------------------------------------------------------------------------
// transpose_x: raw x NCHW -> NHWC bf16.
// ---------------------------------------------------------------------------
template <bool F32>
__device__ __forceinline__ void transpose_body(const void* x, ushort_t* xnb) {
    __shared__ float tile[CIN][64 + 1];
    int blk  = blockIdx.x;
    int b    = blk >> 8;
    int pix0 = (blk & 255) * 64;
    int t    = threadIdx.x;
    int lane = t & 63;
    int grp  = t >> 6;
#pragma unroll
    for (int r = 0; r < 16; ++r) {
        int ci = r * 4 + grp;
        tile[ci][lane] = ld_in<F32>(x, (long)(b * CIN + ci) * HW + pix0 + lane);
    }
    __syncthreads();
#pragma unroll
    for (int r = 0; r < 16; ++r) {
        int px = r * 4 + grp;
        xnb[(size_t)(b * HW + pix0 + px) * CIN + lane] = f2us_bf(tile[lane][px]);
    }
}

__global__ __launch_bounds__(256) void transpose_x(const void* __restrict__ x,
                                                   const float* __restrict__ flag,
                                                   ushort_t* __restrict__ xnb) {
    if (flag[0] != 0.0f) transpose_body<true>(x, xnb);
    else                 transpose_body<false>(x, xnb);
}

// ---------------------------------------------------------------------------
// conv_mfma: implicit-GEMM 3x3 conv -> 27 ch. 1024 thr / 256 px / 16 waves.
// NEW: the 3x3 taps are REGULAR, so the block's whole input footprint is
// rows y0-1..y0+2 = 4 contiguous 16KB NHWC rows = 64KB -> stage in LDS
// (coalesced uint4, XOR-swizzled 16B slots on BOTH write and read) and turn
// the 18 per-lane L2 gathers into short ds_reads. MFMA order unchanged.
// LDS = 36.9KB (B) + 65.5KB (x-tile) = 102.4KB.
// ---------------------------------------------------------------------------
__global__ __launch_bounds__(1024, 4) void conv_mfma(
        const ushort_t* __restrict__ xnb,
        const ushort_t* __restrict__ wcats,
        const float* __restrict__ bias,
        float* __restrict__ off2,
        float* __restrict__ mask_ws) {
    __shared__ uint4 ldsB4[2304];    // 36,864 B
    __shared__ uint4 ldsX4[4096];    // 65,536 B : 4 rows x 128 px x 8 chunks

    int t    = threadIdx.x;
    int bid  = blockIdx.x;
    int sbid = (bid & 7) * 64 + (bid >> 3);   // 512 = 8 XCDs x 64, bijective
    int pix0 = sbid * 256;
    int b    = pix0 >> 14;
    int rem0 = pix0 & 16383;
    int y0   = rem0 >> 7;                     // first of the 2 output rows

    const uint4* ws4 = (const uint4*)wcats;
#pragma unroll
    for (int i = t; i < 2304; i += 1024) ldsB4[i] = ws4[i];

    // stage x rows y0-1..y0+2 (one 16B chunk per thread per row; row = 1024
    // uint4). Swizzle: chunk c16 (0..7 within a pixel) -> c16 ^ (x & 7).
    const uint4* xrow4 = (const uint4*)(xnb + (size_t)b * HW * CIN);
    int sxq  = t >> 3;
    int sc16 = t & 7;
#pragma unroll
    for (int r = 0; r < 4; ++r) {
        int gy = y0 - 1 + r;
        if (gy >= 0 && gy < H_) {
            uint4 v = xrow4[(size_t)gy * 1024 + t];
            ldsX4[r * 1024 + sxq * 8 + (sc16 ^ (sxq & 7))] = v;
        }
    }
    __syncthreads();

    int wave = t >> 6, lane = t & 63, mrow = lane & 15, quad = lane >> 4;
    int px_l = wave * 16 + mrow;
    int ly   = px_l >> 7;            // local output row 0/1
    int xp   = px_l & 127;

    // preload all 9 taps from the LDS tile (short-latency, fully pipelined)
    uint4 af0[9], af1[9];
#pragma unroll
    for (int kk = 0; kk < 9; ++kk) {
        int ty = kk / 3, tx = kk % 3;
        int tr = ly + ty;                        // tile row 0..3
        int gy = y0 - 1 + tr;
        int xq = xp + tx - 1;
        bool ok = (gy >= 0) && (gy < H_) && (xq >= 0) && (xq < W_);
        int xc = min(max(xq, 0), W_ - 1);
        int base = tr * 1024 + xc * 8;
        uint4 a0 = ldsX4[base + ((quad    ) ^ (xc & 7))];
        uint4 a1 = ldsX4[base + ((quad + 4) ^ (xc & 7))];
        af0[kk] = ok ? a0 : make_uint4(0, 0, 0, 0);
        af1[kk] = ok ? a1 : make_uint4(0, 0, 0, 0);
    }

    f32x4 acc[2];
    acc[0] = (f32x4){0.f, 0.f, 0.f, 0.f};
    acc[1] = (f32x4){0.f, 0.f, 0.f, 0.f};
    const ushort_t* ldsB = (const ushort_t*)ldsB4;
#pragma unroll
    for (int kk = 0; kk < 9; ++kk) {
#pragma unroll
        for (int half = 0; half < 2; ++half) {
            int ks = kk * 2 + half;
            U4B a; a.u = half ? af1[kk] : af0[kk];
#pragma unroll
            for (int n = 0; n < 2; ++n) {
                bf16x8 bf = *(const bf16x8*)(ldsB + ((ks * 2 + n) * 64 + lane) * 8);
                acc[n] = __builtin_amdgcn_mfma_f32_16x16x32_bf16(a.v, bf, acc[n], 0, 0, 0);
            }
        }
    }

    // epilogue
#pragma unroll
    for (int n = 0; n < 2; ++n) {
        int co2 = n * 16 + mrow;
        if (co2 >= 27) continue;
        float bs = bias[co2];
#pragma unroll
        for (int r = 0; r < 4; ++r) {
            int px = wave * 16 + quad * 4 + r;
            float v = acc[n][r] + bs;
            if (co2 < 18) {
                off2[((size_t)(b * 9 + (co2 >> 1)) * HW + rem0 + px) * 2 + (co2 & 1)] = v;
            } else {
                mask_ws[(size_t)(b * 9 + (co2 - 18)) * HW + rem0 + px] =
                    1.0f / (1.0f + __expf(-v));
            }
        }
    }
}

// ---------------------------------------------------------------------------
// deform helpers — HALF-TAP pipeline granularity, lookahead 2. (Round-3 best)
// ---------------------------------------------------------------------------
__device__ __forceinline__ void compute_tap(int yp_t, int xp_t,
                                            float oy, float ox, float mk,
                                            int* ofs, float* wg) {
    float py  = (float)yp_t + oy;
    float pxf = (float)xp_t + ox;
    float y0f = floorf(py), x0f = floorf(pxf);
    int yi = (int)y0f, xi = (int)x0f;
    float wy1 = py - y0f, wx1 = pxf - x0f;
    float wy0 = 1.0f - wy1, wx0 = 1.0f - wx1;
    int ya  = min(max(yi, 0), H_ - 1);
    int yb  = min(max(yi + 1, 0), H_ - 1);
    int xa  = min(max(xi, 0), W_ - 1);
    int xb2 = min(max(xi + 1, 0), W_ - 1);
    bool vy0 = (yi >= 0) & (yi < H_);
    bool vy1 = (yi >= -1) & (yi < H_ - 1);
    bool vx0 = (xi >= 0) & (xi < W_);
    bool vx1 = (xi >= -1) & (xi < W_ - 1);
    float m0 = mk * wy0, m1 = mk * wy1;
    wg[0] = (vy0 & vx0) ? m0 * wx0 : 0.0f;
    wg[1] = (vy0 & vx1) ? m0 * wx1 : 0.0f;
    wg[2] = (vy1 & vx0) ? m1 * wx0 : 0.0f;
    wg[3] = (vy1 & vx1) ? m1 * wx1 : 0.0f;
    int ra = ya << 13, rb = yb << 13;   // y * W_ * CIN
    int ca = xa << 6,  cb_ = xb2 << 6;  // x * CIN
    ofs[0] = ra + ca;  ofs[1] = ra + cb_;
    ofs[2] = rb + ca;  ofs[3] = rb + cb_;
}

__device__ __forceinline__ void issue_half(const ushort_t* __restrict__ xb,
                                           const int* ofs, int hoff, uint4* cb) {
#pragma unroll
    for (int c = 0; c < 4; ++c)
        cb[c] = *(const uint4*)(xb + ofs[c] + hoff);
}

__device__ __forceinline__ void consume_half(int ks, const uint4* cb,
                                             const float* wg,
                                             const ushort_t* __restrict__ ldsB,
                                             int lane, f32x4* acc) {
    float2 v2[4];
#pragma unroll
    for (int j = 0; j < 4; ++j) v2[j] = make_float2(0.f, 0.f);
#pragma unroll
    for (int c = 0; c < 4; ++c) {
        float w = wg[c];
        unsigned int ww[4] = {cb[c].x, cb[c].y, cb[c].z, cb[c].w};
#pragma unroll
        for (int j = 0; j < 4; ++j) {
            v2[j].x = fmaf(w, lo_f(ww[j]), v2[j].x);
            v2[j].y = fmaf(w, hi_f(ww[j]), v2[j].y);
        }
    }
    U4B a;
    a.u = make_uint4(pack2(v2[0].x, v2[0].y), pack2(v2[1].x, v2[1].y),
                     pack2(v2[2].x, v2[2].y), pack2(v2[3].x, v2[3].y));
    const ushort_t* bbase = ldsB + ((size_t)(ks * 8) * 64 + lane) * 8;
    __builtin_amdgcn_s_setprio(1);
#pragma unroll
    for (int n = 0; n < 8; ++n) {
        bf16x8 bf = *(const bf16x8*)(bbase + n * 64 * 8);
        acc[n] = __builtin_amdgcn_mfma_f32_16x16x32_bf16(a.v, bf, acc[n], 0, 0, 0);
    }
    __builtin_amdgcn_s_setprio(0);
}

// ---------------------------------------------------------------------------
// deform_mfma: fused bilinear sampling + GEMM (Round-3 best: 86.5us).
// XCD-chunked swizzle; half-tap pipeline, lookahead-2 ring; one barrier.
// ---------------------------------------------------------------------------
__global__ __launch_bounds__(1024, 4) void deform_mfma(
        const ushort_t* __restrict__ xnb,
        const float* __restrict__ off2,
        const float* __restrict__ mask_ws,
        const ushort_t* __restrict__ wTs,
        ushort_t* __restrict__ prebn,
        float* __restrict__ gstat) {
    __shared__ uint4 ldsB4[9216];    // 147,456 B
    __shared__ float red[256];

    int t    = threadIdx.x;
    int bid  = blockIdx.x;
    int sbid = (bid & 7) * 64 + (bid >> 3);   // 512 = 8 XCDs x 64, bijective
    int pix0 = sbid * 256;
    int b    = pix0 >> 14;
    int rem0 = pix0 & 16383;

    const uint4* ws4 = (const uint4*)wTs;
#pragma unroll
    for (int i = 0; i < 9; ++i) ldsB4[i * 1024 + t] = ws4[i * 1024 + t];
    if (t < 256) red[t] = 0.0f;

    int wave = t >> 6, lane = t & 63, mrow = lane & 15, quad = lane >> 4;
    int px_l = wave * 16 + mrow;
    int remp = rem0 + px_l;
    int yp = remp >> 7, xp = remp & 127;
    const ushort_t* xb = xnb + (size_t)b * HW * CIN + quad * 8;
    size_t obase = (size_t)b * 9 * HW + remp;

    // 2-slot (even/odd tap) offset+mask prefetch: taps 0 and 1 pre-barrier.
    float2 oE = *(const float2*)(off2 + obase * 2);
    float2 oO = *(const float2*)(off2 + (obase + HW) * 2);
    float mkE = mask_ws[obase];
    float mkO = mask_ws[obase + HW];
    __syncthreads();

    f32x4 acc[8];
#pragma unroll
    for (int n = 0; n < 8; ++n) acc[n] = (f32x4){0.f, 0.f, 0.f, 0.f};
    const ushort_t* ldsB = (const ushort_t*)ldsB4;

    // addr/weight slots by tap parity; 3-deep corner-buffer ring by hs%3
    int   ofs[2][4];
    float wg[2][4];
    uint4 cb[3][4];

    // prologue: tap0 addresses, issue hs=0 and hs=1; refill E slot with tap2
    compute_tap(yp - 1, xp - 1, oE.x, oE.y, mkE, ofs[0], wg[0]);
    issue_half(xb, ofs[0], 0,  cb[0]);
    issue_half(xb, ofs[0], 32, cb[1]);
    oE  = *(const float2*)(off2 + (obase + (size_t)2 * HW) * 2);
    mkE = mask_ws[obase + (size_t)2 * HW];
    __builtin_amdgcn_sched_barrier(0);

#pragma unroll
    for (int hs = 0; hs < 18; ++hs) {
        const int hs2 = hs + 2;
        if (hs2 < 18) {
            const int kk2 = hs2 >> 1;   // tap being issued
            const int s2  = hs2 % 3;    // ring slot being filled
            if ((hs2 & 1) == 0) {
                const int tp2 = kk2 & 1;
                float ooy = tp2 ? oO.x : oE.x;
                float oox = tp2 ? oO.y : oE.y;
                float omk = tp2 ? mkO  : mkE;
                compute_tap(yp + kk2 / 3 - 1, xp + kk2 % 3 - 1, ooy, oox, omk,
                            ofs[tp2], wg[tp2]);
                issue_half(xb, ofs[tp2], 0, cb[s2]);
                if (kk2 + 2 <= 8) {   // refill this parity slot with tap kk2+2
                    float2 o = *(const float2*)(off2 + (obase + (size_t)(kk2 + 2) * HW) * 2);
                    float  m = mask_ws[obase + (size_t)(kk2 + 2) * HW];
                    if (tp2) { oO = o; mkO = m; } else { oE = o; mkE = m; }
                }
            } else {
                issue_half(xb, ofs[kk2 & 1], 32, cb[s2]);
            }
        }
        __builtin_amdgcn_sched_barrier(0);
        consume_half(hs, cb[hs % 3], wg[(hs >> 1) & 1], ldsB, lane, acc);
    }

    // ---- epilogue: bf16 NHWC store + BN stats (shuffle-reduce) ----
#pragma unroll
    for (int n = 0; n < 8; ++n) {
        int co = n * 16 + mrow;
        float s = 0.f, ss = 0.f;
#pragma unroll
        for (int r = 0; r < 4; ++r) {
            int pg = pix0 + wave * 16 + quad * 4 + r;
            float v = acc[n][r];
            prebn[(size_t)pg * COUT + co] = f2us_bf(v);
            s += v;
            ss += v * v;
        }
        s  += __shfl_xor(s, 16, 64);
        s  += __shfl_xor(s, 32, 64);
        ss += __shfl_xor(ss, 16, 64);
        ss += __shfl_xor(ss, 32, 64);
        if (quad == 0) {
            atomicAdd(&red[co], s);
            atomicAdd(&red[128 + co], ss);
        }
    }
    __syncthreads();
    if (t < 256) atomicAdd(&gstat[(bid & 15) * 256 + t], red[t]);
}

// ---------------------------------------------------------------------------
// bn_apply_t: derive mean/rstd from gstat; read pre-BN bf16 NHWC with uint4
// vector loads (was scalar ushort: G13 violation), normalize+ReLU into the
// LDS transpose tile, write f32 NCHW with float4 stores.
// ---------------------------------------------------------------------------
__global__ __launch_bounds__(256) void bn_apply_t(const ushort_t* __restrict__ prebn,
                                                  const float* __restrict__ gstat,
                                                  float* __restrict__ out) {
    __shared__ float tile[128 * 65];
    __shared__ float mvs[256];
    int t = threadIdx.x;
    if (t < 128) {
        float s = 0.f, ss = 0.f;
#pragma unroll
        for (int part = 0; part < 16; ++part) {
            s  += gstat[part * 256 + t];
            ss += gstat[part * 256 + 128 + t];
        }
        const float invN = 1.0f / (float)NPIX;
        float mean = s * invN;
        float var  = ss * invN - mean * mean;
        if (!isfinite(mean)) mean = 0.0f;
        float r = rsqrtf(fmaxf(var, 0.0f) + 1e-5f);
        if (!isfinite(r)) r = 1.0f;
        mvs[t]       = mean;
        mvs[128 + t] = r;
    }
    __syncthreads();
    int pix0 = blockIdx.x * 64;
    int b    = pix0 >> 14;
    int rem0 = pix0 & 16383;
    const uint4* src4 = (const uint4*)(prebn + (size_t)pix0 * COUT);
#pragma unroll
    for (int r = 0; r < 4; ++r) {
        int i  = r * 256 + t;        // uint4 index 0..1023
        uint4 v = src4[i];
        int p  = i >> 4;             // pixel 0..63
        int c0 = (i & 15) * 8;       // channel base
        unsigned int w[4] = {v.x, v.y, v.z, v.w};
#pragma unroll
        for (int j = 0; j < 4; ++j) {
            int c = c0 + j * 2;
            float f0 = lo_f(w[j]);
            float f1 = hi_f(w[j]);
            tile[c * 65 + p]       = fmaxf((f0 - mvs[c])     * mvs[128 + c],     0.0f);
            tile[(c + 1) * 65 + p] = fmaxf((f1 - mvs[c + 1]) * mvs[128 + c + 1], 0.0f);
        }
    }
    __syncthreads();
#pragma unroll
    for (int r = 0; r < 8; ++r) {
        int i  = r * 256 + t;        // float4 index 0..2047
        int c2 = i >> 4;             // 0..127
        int q  = (i & 15) * 4;       // 0..60
        float4 w4 = make_float4(tile[c2 * 65 + q],     tile[c2 * 65 + q + 1],
                                tile[c2 * 65 + q + 2], tile[c2 * 65 + q + 3]);
        *(float4*)(out + (size_t)(b * COUT + c2) * HW + rem0 + q) = w4;
    }
}

// ---------------------------------------------------------------------------
extern "C" void kernel_launch(void* const* d_in, const int* in_sizes, int n_in,
                              void* d_out, int out_size, void* d_ws, size_t ws_size,
                              hipStream_t stream) {
    (void)in_sizes; (void)n_in; (void)out_size; (void)ws_size;
    const void* x     = d_in[0];
    const void* offw  = d_in[1];
    const void* offb  = d_in[2];
    const void* maskw = d_in[3];
    const void* maskb = d_in[4];
    const void* convw = d_in[5];

    float* ws       = (float*)d_ws;
    float* off2     = ws;                      // 2,359,296 f32 (y,x interleaved)
    float* mask_ws  = off2 + 2359296;          // 1,179,648 f32
    float* bias     = mask_ws + 1179648;       //        32 f32
    float* gstat    = bias + 32;               //     4,096 f32
    float* flag     = gstat + 4096;            //        16 f32
    ushort_t* wTs   = (ushort_t*)(flag + 16);  //    73,728 bf16 (frag-linear)
    ushort_t* wcats = wTs + 73728;             //    18,432 bf16 (frag-linear)
    ushort_t* xnb   = wcats + 18432;           // 8,388,608 bf16 (NHWC x)
    ushort_t* prebn = xnb + 8388608;           // 16,777,216 bf16 (NHWC pre-BN)
    float* out      = (float*)d_out;

    detect_zero<<<1, 256, 0, stream>>>((const uint4*)x, flag, gstat);
    prep_weights<<<361, 256, 0, stream>>>(offw, offb, maskw, maskb, convw, flag, wTs, wcats, bias);
    transpose_x<<<2048, 256, 0, stream>>>(x, flag, xnb);
    conv_mfma<<<512, 1024, 0, stream>>>(xnb, wcats, bias, off2, mask_ws);
    deform_mfma<<<512, 1024, 0, stream>>>(xnb, off2, mask_ws, wTs, prebn, gstat);
    bn_apply_t<<<2048, 256, 0, stream>>>(prebn, gstat, out);
}

// Round 6
// 201.981 us; speedup vs baseline: 1.2494x; 1.0271x over previous
//
#include <hip/hip_runtime.h>
#include <hip/hip_bf16.h>

// Problem constants
#define H_ 128
#define W_ 128
#define HW 16384          // H*W
#define CIN 64
#define COUT 128
#define KK9 9
#define BATCH 8
#define NPIX (BATCH * HW) // 131072
#define KDIM 576          // CIN*KK9

typedef short bf16x8 __attribute__((ext_vector_type(8)));
typedef float f32x4  __attribute__((ext_vector_type(4)));
typedef unsigned short ushort_t;

union U4B { uint4 u; bf16x8 v; };

__device__ __forceinline__ float us2f(unsigned short u) {
    unsigned int v = ((unsigned int)u) << 16;
    float f;
    __builtin_memcpy(&f, &v, 4);
    return f;
}
__device__ __forceinline__ float lo_f(unsigned int w) {
    unsigned int v = w << 16;
    float f;
    __builtin_memcpy(&f, &v, 4);
    return f;
}
__device__ __forceinline__ float hi_f(unsigned int w) {
    unsigned int v = w & 0xffff0000u;
    float f;
    __builtin_memcpy(&f, &v, 4);
    return f;
}
__device__ __forceinline__ unsigned short f2us_bf(float f) {
    __hip_bfloat16 h = __float2bfloat16(f);
    unsigned short u;
    __builtin_memcpy(&u, &h, 2);
    return u;
}
__device__ __forceinline__ unsigned int pack2(float a, float b) {
    return (unsigned int)f2us_bf(a) | ((unsigned int)f2us_bf(b) << 16);
}

template <bool F32>
__device__ __forceinline__ float ld_in(const void* p, long i) {
    if (F32) return ((const float*)p)[i];
    return us2f(((const unsigned short*)p)[i]);
}

// ---------------------------------------------------------------------------
// detect_zero: dtype probe (1 wave, vector loads, ballot) + zero gstat.
// ---------------------------------------------------------------------------
__global__ void detect_zero(const uint4* __restrict__ xr4,
                            float* __restrict__ flag,
                            float* __restrict__ gstat) {
    int t = threadIdx.x;   // 256
#pragma unroll
    for (int i = 0; i < 16; ++i) gstat[i * 256 + t] = 0.0f;
    if (t < 64) {
        uint4 v = xr4[t];
        unsigned int w[4] = {v.x, v.y, v.z, v.w};
        int big = 0;
#pragma unroll
        for (int q = 0; q < 4; ++q) {
            big += (((w[q] >> 7)  & 0xFF) >= 0xC0);
            big += (((w[q] >> 23) & 0xFF) >= 0xC0);
        }
        unsigned long long m = __ballot(big > 0);
        if (t == 0) flag[0] = m ? 1.0f : 0.0f;
    }
}

// ---------------------------------------------------------------------------
// prep_weights: weights in MFMA-fragment-linear order.
// ---------------------------------------------------------------------------
template <bool F32>
__device__ __forceinline__ void prep_body(const void* offw, const void* offb,
                                          const void* maskw, const void* maskb,
                                          const void* convw,
                                          ushort_t* wTs, ushort_t* wcats,
                                          float* bias, int i) {
    if (i < 73728) {
        int j = i & 7, lane = (i >> 3) & 63, n = (i >> 9) & 7, ks = i >> 12;
        int co = n * 16 + (lane & 15);
        int k  = ks * 32 + ((lane >> 4) << 3) + j;
        int kk = k >> 6, ci = k & 63;
        wTs[i] = f2us_bf(ld_in<F32>(convw, (long)co * KDIM + ci * 9 + kk));
    } else if (i < 73728 + 18432) {
        int i2 = i - 73728;
        int j = i2 & 7, lane = (i2 >> 3) & 63, n = (i2 >> 9) & 1, ks = i2 >> 10;
        int co2 = n * 16 + (lane & 15);
        int k   = ks * 32 + ((lane >> 4) << 3) + j;
        int kk = k >> 6, ci = k & 63;
        float v = 0.0f;
        if (co2 < 18)      v = ld_in<F32>(offw,  (long)co2 * KDIM + ci * 9 + kk);
        else if (co2 < 27) v = ld_in<F32>(maskw, (long)(co2 - 18) * KDIM + ci * 9 + kk);
        wcats[i2] = f2us_bf(v);
    } else if (i < 73728 + 18432 + 32) {
        int j = i - 73728 - 18432;
        float v = 0.0f;
        if (j < 18)      v = ld_in<F32>(offb, j);
        else if (j < 27) v = ld_in<F32>(maskb, j - 18);
        bias[j] = v;
    }
}

__global__ void prep_weights(const void* __restrict__ offw,
                             const void* __restrict__ offb,
                             const void* __restrict__ maskw,
                             const void* __restrict__ maskb,
                             const void* __restrict__ convw,
                             const float* __restrict__ flag,
                             ushort_t* __restrict__ wTs,
                             ushort_t* __restrict__ wcats,
                             float* __restrict__ bias) {
    int i = blockIdx.x * 256 + threadIdx.x;
    if (flag[0] != 0.0f)
        prep_body<true>(offw, offb, maskw, maskb, convw, wTs, wcats, bias, i);
    else
        prep_body<false>(offw, offb, maskw, maskb, convw, wTs, wcats, bias, i);
}

// ---------------------------------------------------------------------------
// transpose_x: raw x NCHW -> NHWC bf16. Vectorized (G13): float4/ushort4
// reads (16B/8B per lane), ushort4 writes (8B per lane), padded LDS tile.
// ---------------------------------------------------------------------------
template <bool F32>
__device__ __forceinline__ void transpose_body(const void* x, ushort_t* xnb) {
    __shared__ float tile[CIN * 65];
    int blk  = blockIdx.x;
    int b    = blk >> 8;
    int pix0 = (blk & 255) * 64;
    int t    = threadIdx.x;
#pragma unroll
    for (int pass = 0; pass < 4; ++pass) {
        int slot = pass * 256 + t;
        int ci = slot >> 4;          // 0..63
        int f4 = slot & 15;          // 0..15 (4-px chunk)
        long base = (long)(b * CIN + ci) * HW + pix0 + f4 * 4;
        float v0, v1, v2, v3;
        if (F32) {
            float4 v = *(const float4*)((const float*)x + base);
            v0 = v.x; v1 = v.y; v2 = v.z; v3 = v.w;
        } else {
            ushort4 u = *(const ushort4*)((const ushort_t*)x + base);
            v0 = us2f(u.x); v1 = us2f(u.y); v2 = us2f(u.z); v3 = us2f(u.w);
        }
        tile[ci * 65 + f4 * 4 + 0] = v0;
        tile[ci * 65 + f4 * 4 + 1] = v1;
        tile[ci * 65 + f4 * 4 + 2] = v2;
        tile[ci * 65 + f4 * 4 + 3] = v3;
    }
    __syncthreads();
#pragma unroll
    for (int pass = 0; pass < 4; ++pass) {
        int slot = pass * 256 + t;
        int px = slot >> 4;          // 0..63
        int c4 = slot & 15;          // 0..15 (4-ch chunk)
        ushort4 o;
        o.x = f2us_bf(tile[(c4 * 4 + 0) * 65 + px]);
        o.y = f2us_bf(tile[(c4 * 4 + 1) * 65 + px]);
        o.z = f2us_bf(tile[(c4 * 4 + 2) * 65 + px]);
        o.w = f2us_bf(tile[(c4 * 4 + 3) * 65 + px]);
        *(ushort4*)(xnb + (size_t)(b * HW + pix0 + px) * CIN + c4 * 4) = o;
    }
}

__global__ __launch_bounds__(256) void transpose_x(const void* __restrict__ x,
                                                   const float* __restrict__ flag,
                                                   ushort_t* __restrict__ xnb) {
    if (flag[0] != 0.0f) transpose_body<true>(x, xnb);
    else                 transpose_body<false>(x, xnb);
}

// ---------------------------------------------------------------------------
// deform helpers (Round-3 best inner loop; unchanged math).
// ---------------------------------------------------------------------------
__device__ __forceinline__ void compute_tap(int yp_t, int xp_t,
                                            float oy, float ox, float mk,
                                            int* ofs, float* wg) {
    float py  = (float)yp_t + oy;
    float pxf = (float)xp_t + ox;
    float y0f = floorf(py), x0f = floorf(pxf);
    int yi = (int)y0f, xi = (int)x0f;
    float wy1 = py - y0f, wx1 = pxf - x0f;
    float wy0 = 1.0f - wy1, wx0 = 1.0f - wx1;
    int ya  = min(max(yi, 0), H_ - 1);
    int yb  = min(max(yi + 1, 0), H_ - 1);
    int xa  = min(max(xi, 0), W_ - 1);
    int xb2 = min(max(xi + 1, 0), W_ - 1);
    bool vy0 = (yi >= 0) & (yi < H_);
    bool vy1 = (yi >= -1) & (yi < H_ - 1);
    bool vx0 = (xi >= 0) & (xi < W_);
    bool vx1 = (xi >= -1) & (xi < W_ - 1);
    float m0 = mk * wy0, m1 = mk * wy1;
    wg[0] = (vy0 & vx0) ? m0 * wx0 : 0.0f;
    wg[1] = (vy0 & vx1) ? m0 * wx1 : 0.0f;
    wg[2] = (vy1 & vx0) ? m1 * wx0 : 0.0f;
    wg[3] = (vy1 & vx1) ? m1 * wx1 : 0.0f;
    int ra = ya << 13, rb = yb << 13;   // y * W_ * CIN
    int ca = xa << 6,  cb_ = xb2 << 6;  // x * CIN
    ofs[0] = ra + ca;  ofs[1] = ra + cb_;
    ofs[2] = rb + ca;  ofs[3] = rb + cb_;
}

__device__ __forceinline__ void issue_half(const ushort_t* __restrict__ xb,
                                           const int* ofs, int hoff, uint4* cb) {
#pragma unroll
    for (int c = 0; c < 4; ++c)
        cb[c] = *(const uint4*)(xb + ofs[c] + hoff);
}

__device__ __forceinline__ void consume_half(int slot, const uint4* cb,
                                             const float* wg,
                                             const ushort_t* __restrict__ ldsB,
                                             int lane, f32x4* acc) {
    float2 v2[4];
#pragma unroll
    for (int j = 0; j < 4; ++j) v2[j] = make_float2(0.f, 0.f);
#pragma unroll
    for (int c = 0; c < 4; ++c) {
        float w = wg[c];
        unsigned int ww[4] = {cb[c].x, cb[c].y, cb[c].z, cb[c].w};
#pragma unroll
        for (int j = 0; j < 4; ++j) {
            v2[j].x = fmaf(w, lo_f(ww[j]), v2[j].x);
            v2[j].y = fmaf(w, hi_f(ww[j]), v2[j].y);
        }
    }
    U4B a;
    a.u = make_uint4(pack2(v2[0].x, v2[0].y), pack2(v2[1].x, v2[1].y),
                     pack2(v2[2].x, v2[2].y), pack2(v2[3].x, v2[3].y));
    const ushort_t* bbase = ldsB + ((size_t)(slot * 8) * 64 + lane) * 8;
    __builtin_amdgcn_s_setprio(1);
#pragma unroll
    for (int n = 0; n < 8; ++n) {
        bf16x8 bf = *(const bf16x8*)(bbase + n * 64 * 8);
        acc[n] = __builtin_amdgcn_mfma_f32_16x16x32_bf16(a.v, bf, acc[n], 0, 0, 0);
    }
    __builtin_amdgcn_s_setprio(0);
}

// ---------------------------------------------------------------------------
// fused_conv_deform: conv (offset/mask) phase + deform phase in ONE kernel.
// 512 blocks (XCD-chunked) x 1024 thr / 256 px. LDS = 128 KB:
//   P region  lds[0..6400)  : conv = {convB 2304 | x-tile 4096}; deform =
//                             {B K-half 4608} (restaged mid-loop, R4-style)
//   C region  lds[6400..]   : offL float2[9][256] + maskS f32[9][256] +
//                             red f32[256]  (persistent across phases)
// Deletes the separate conv_mfma launch and the 28 MB off2/mask HBM
// round-trip; deform inner loop is byte-identical R3-best (85.5us), with
// offset/mask prefetch sourced from LDS instead of global.
// ---------------------------------------------------------------------------
__global__ __launch_bounds__(1024, 4) void fused_conv_deform(
        const ushort_t* __restrict__ xnb,
        const ushort_t* __restrict__ wcats,
        const float* __restrict__ bias,
        const ushort_t* __restrict__ wTs,
        ushort_t* __restrict__ prebn,
        float* __restrict__ gstat) {
    __shared__ uint4 lds[8192];   // 131,072 B

    float2* offL  = (float2*)(lds + 6400);   // 9*256 float2 (18,432 B)
    float*  maskS = (float*) (lds + 7552);   // 9*256 f32    ( 9,216 B)
    float*  red   = (float*) (lds + 8128);   // 256 f32      ( 1,024 B)

    int t    = threadIdx.x;
    int bid  = blockIdx.x;
    int sbid = (bid & 7) * 64 + (bid >> 3);   // 512 = 8 XCDs x 64, bijective
    int pix0 = sbid * 256;
    int b    = pix0 >> 14;
    int rem0 = pix0 & 16383;
    int y0   = rem0 >> 7;

    // ---- phase 0: stage convB + 4-row x-tile (swizzled) ----
    const uint4* wc4 = (const uint4*)wcats;
    for (int i = t; i < 2304; i += 1024) lds[i] = wc4[i];
    const uint4* xrow4 = (const uint4*)(xnb + (size_t)b * HW * CIN);
    int sxq = t >> 3, sc16 = t & 7;
#pragma unroll
    for (int r = 0; r < 4; ++r) {
        int gy = y0 - 1 + r;
        if (gy >= 0 && gy < H_) {
            uint4 v = xrow4[(size_t)gy * 1024 + t];
            lds[2304 + r * 1024 + sxq * 8 + (sc16 ^ (sxq & 7))] = v;
        }
    }
    if (t < 256) red[t] = 0.0f;
    __syncthreads();

    int wave = t >> 6, lane = t & 63, mrow = lane & 15, quad = lane >> 4;
    int px_l = wave * 16 + mrow;

    // ---- phase 1: conv 27-ch -> offL/maskS in LDS ----
    {
        int ly = px_l >> 7;
        int xp = px_l & 127;
        uint4 af0[9], af1[9];
#pragma unroll
        for (int kk = 0; kk < 9; ++kk) {
            int ty = kk / 3, tx = kk % 3;
            int tr = ly + ty;
            int gy = y0 - 1 + tr;
            int xq = xp + tx - 1;
            bool ok = (gy >= 0) && (gy < H_) && (xq >= 0) && (xq < W_);
            int xc = min(max(xq, 0), W_ - 1);
            int base = 2304 + tr * 1024 + xc * 8;
            uint4 a0 = lds[base + ((quad    ) ^ (xc & 7))];
            uint4 a1 = lds[base + ((quad + 4) ^ (xc & 7))];
            af0[kk] = ok ? a0 : make_uint4(0, 0, 0, 0);
            af1[kk] = ok ? a1 : make_uint4(0, 0, 0, 0);
        }
        f32x4 cacc[2];
        cacc[0] = (f32x4){0.f, 0.f, 0.f, 0.f};
        cacc[1] = (f32x4){0.f, 0.f, 0.f, 0.f};
        const ushort_t* ldsBc = (const ushort_t*)lds;
#pragma unroll
        for (int kk = 0; kk < 9; ++kk) {
#pragma unroll
            for (int half = 0; half < 2; ++half) {
                int ks = kk * 2 + half;
                U4B a; a.u = half ? af1[kk] : af0[kk];
#pragma unroll
                for (int n = 0; n < 2; ++n) {
                    bf16x8 bf = *(const bf16x8*)(ldsBc + ((ks * 2 + n) * 64 + lane) * 8);
                    cacc[n] = __builtin_amdgcn_mfma_f32_16x16x32_bf16(a.v, bf, cacc[n], 0, 0, 0);
                }
            }
        }
#pragma unroll
        for (int n = 0; n < 2; ++n) {
            int co2 = n * 16 + mrow;
            if (co2 >= 27) continue;
            float bs = bias[co2];
#pragma unroll
            for (int r = 0; r < 4; ++r) {
                int px = wave * 16 + quad * 4 + r;
                float v = cacc[n][r] + bs;
                if (co2 < 18)
                    ((float*)offL)[((co2 >> 1) * 256 + px) * 2 + (co2 & 1)] = v;
                else
                    maskS[(co2 - 18) * 256 + px] = 1.0f / (1.0f + __expf(-v));
            }
        }
    }
    __syncthreads();   // x-tile/convB reads done; offL/maskS visible

    // ---- phase 2: stage deform B half0 + gather-ring prologue ----
    const uint4* ws4 = (const uint4*)wTs;
    for (int i = t; i < 4608; i += 1024) lds[i] = ws4[i];

    int remp = rem0 + px_l;
    int yp  = remp >> 7, xp2 = remp & 127;
    const ushort_t* xb = xnb + (size_t)b * HW * CIN + quad * 8;

    f32x4 acc[8];
#pragma unroll
    for (int n = 0; n < 8; ++n) acc[n] = (f32x4){0.f, 0.f, 0.f, 0.f};

    int   ofs[2][4];
    float wg[2][4];
    uint4 cb[3][4];

    float2 oE  = offL[px_l];           float mkE = maskS[px_l];
    float2 oO  = offL[256 + px_l];     float mkO = maskS[256 + px_l];
    compute_tap(yp - 1, xp2 - 1, oE.x, oE.y, mkE, ofs[0], wg[0]);
    issue_half(xb, ofs[0], 0,  cb[0]);
    issue_half(xb, ofs[0], 32, cb[1]);
    oE = offL[2 * 256 + px_l];  mkE = maskS[2 * 256 + px_l];
    __builtin_amdgcn_sched_barrier(0);
    __syncthreads();   // B half0 visible

    const ushort_t* ldsB = (const ushort_t*)lds;

#pragma unroll
    for (int hs = 0; hs < 9; ++hs) {
        const int hs2 = hs + 2;                // 2..10, always valid
        {
            const int kk2 = hs2 >> 1;
            const int s2  = hs2 % 3;
            if ((hs2 & 1) == 0) {
                const int tp2 = kk2 & 1;
                float ooy = tp2 ? oO.x : oE.x;
                float oox = tp2 ? oO.y : oE.y;
                float omk = tp2 ? mkO  : mkE;
                compute_tap(yp + kk2 / 3 - 1, xp2 + kk2 % 3 - 1, ooy, oox, omk,
                            ofs[tp2], wg[tp2]);
                issue_half(xb, ofs[tp2], 0, cb[s2]);
                if (kk2 + 2 <= 8) {
                    float2 o = offL[(kk2 + 2) * 256 + px_l];
                    float  m = maskS[(kk2 + 2) * 256 + px_l];
                    if (tp2) { oO = o; mkO = m; } else { oE = o; mkE = m; }
                }
            } else {
                issue_half(xb, ofs[kk2 & 1], 32, cb[s2]);
            }
        }
        __builtin_amdgcn_sched_barrier(0);
        consume_half(hs, cb[hs % 3], wg[(hs >> 1) & 1], ldsB, lane, acc);
    }
    __syncthreads();   // half0 reads done
    for (int i = t; i < 4608; i += 1024) lds[i] = ws4[4608 + i];
    __syncthreads();   // half1 visible

#pragma unroll
    for (int hs = 9; hs < 18; ++hs) {
        const int hs2 = hs + 2;
        if (hs2 < 18) {
            const int kk2 = hs2 >> 1;
            const int s2  = hs2 % 3;
            if ((hs2 & 1) == 0) {
                const int tp2 = kk2 & 1;
                float ooy = tp2 ? oO.x : oE.x;
                float oox = tp2 ? oO.y : oE.y;
                float omk = tp2 ? mkO  : mkE;
                compute_tap(yp + kk2 / 3 - 1, xp2 + kk2 % 3 - 1, ooy, oox, omk,
                            ofs[tp2], wg[tp2]);
                issue_half(xb, ofs[tp2], 0, cb[s2]);
                if (kk2 + 2 <= 8) {
                    float2 o = offL[(kk2 + 2) * 256 + px_l];
                    float  m = maskS[(kk2 + 2) * 256 + px_l];
                    if (tp2) { oO = o; mkO = m; } else { oE = o; mkE = m; }
                }
            } else {
                issue_half(xb, ofs[kk2 & 1], 32, cb[s2]);
            }
        }
        __builtin_amdgcn_sched_barrier(0);
        consume_half(hs - 9, cb[hs % 3], wg[(hs >> 1) & 1], ldsB, lane, acc);
    }

    // ---- epilogue: bf16 NHWC store + BN stats (shuffle-reduce) ----
#pragma unroll
    for (int n = 0; n < 8; ++n) {
        int co = n * 16 + mrow;
        float s = 0.f, ss = 0.f;
#pragma unroll
        for (int r = 0; r < 4; ++r) {
            int pg = pix0 + wave * 16 + quad * 4 + r;
            float v = acc[n][r];
            prebn[(size_t)pg * COUT + co] = f2us_bf(v);
            s += v;
            ss += v * v;
        }
        s  += __shfl_xor(s, 16, 64);
        s  += __shfl_xor(s, 32, 64);
        ss += __shfl_xor(ss, 16, 64);
        ss += __shfl_xor(ss, 32, 64);
        if (quad == 0) {
            atomicAdd(&red[co], s);
            atomicAdd(&red[128 + co], ss);
        }
    }
    __syncthreads();
    if (t < 256) atomicAdd(&gstat[(bid & 15) * 256 + t], red[t]);
}

// ---------------------------------------------------------------------------
// bn_apply_t: derive mean/rstd from gstat; vectorized uint4 reads + float4
// writes via padded LDS transpose tile.
// ---------------------------------------------------------------------------
__global__ __launch_bounds__(256) void bn_apply_t(const ushort_t* __restrict__ prebn,
                                                  const float* __restrict__ gstat,
                                                  float* __restrict__ out) {
    __shared__ float tile[128 * 65];
    __shared__ float mvs[256];
    int t = threadIdx.x;
    if (t < 128) {
        float s = 0.f, ss = 0.f;
#pragma unroll
        for (int part = 0; part < 16; ++part) {
            s  += gstat[part * 256 + t];
            ss += gstat[part * 256 + 128 + t];
        }
        const float invN = 1.0f / (float)NPIX;
        float mean = s * invN;
        float var  = ss * invN - mean * mean;
        if (!isfinite(mean)) mean = 0.0f;
        float r = rsqrtf(fmaxf(var, 0.0f) + 1e-5f);
        if (!isfinite(r)) r = 1.0f;
        mvs[t]       = mean;
        mvs[128 + t] = r;
    }
    __syncthreads();
    int pix0 = blockIdx.x * 64;
    int b    = pix0 >> 14;
    int rem0 = pix0 & 16383;
    const uint4* src4 = (const uint4*)(prebn + (size_t)pix0 * COUT);
#pragma unroll
    for (int r = 0; r < 4; ++r) {
        int i  = r * 256 + t;        // uint4 index 0..1023
        uint4 v = src4[i];
        int p  = i >> 4;             // pixel 0..63
        int c0 = (i & 15) * 8;       // channel base
        unsigned int w[4] = {v.x, v.y, v.z, v.w};
#pragma unroll
        for (int j = 0; j < 4; ++j) {
            int c = c0 + j * 2;
            float f0 = lo_f(w[j]);
            float f1 = hi_f(w[j]);
            tile[c * 65 + p]       = fmaxf((f0 - mvs[c])     * mvs[128 + c],     0.0f);
            tile[(c + 1) * 65 + p] = fmaxf((f1 - mvs[c + 1]) * mvs[128 + c + 1], 0.0f);
        }
    }
    __syncthreads();
#pragma unroll
    for (int r = 0; r < 8; ++r) {
        int i  = r * 256 + t;        // float4 index 0..2047
        int c2 = i >> 4;             // 0..127
        int q  = (i & 15) * 4;       // 0..60
        float4 w4 = make_float4(tile[c2 * 65 + q],     tile[c2 * 65 + q + 1],
                                tile[c2 * 65 + q + 2], tile[c2 * 65 + q + 3]);
        *(float4*)(out + (size_t)(b * COUT + c2) * HW + rem0 + q) = w4;
    }
}

// ---------------------------------------------------------------------------
extern "C" void kernel_launch(void* const* d_in, const int* in_sizes, int n_in,
                              void* d_out, int out_size, void* d_ws, size_t ws_size,
                              hipStream_t stream) {
    (void)in_sizes; (void)n_in; (void)out_size; (void)ws_size;
    const void* x     = d_in[0];
    const void* offw  = d_in[1];
    const void* offb  = d_in[2];
    const void* maskw = d_in[3];
    const void* maskb = d_in[4];
    const void* convw = d_in[5];

    float* ws       = (float*)d_ws;
    float* off2     = ws;                      // (unused after fusion)
    float* mask_ws  = off2 + 2359296;          // (unused after fusion)
    float* bias     = mask_ws + 1179648;       //        32 f32
    float* gstat    = bias + 32;               //     4,096 f32
    float* flag     = gstat + 4096;            //        16 f32
    ushort_t* wTs   = (ushort_t*)(flag + 16);  //    73,728 bf16 (frag-linear)
    ushort_t* wcats = wTs + 73728;             //    18,432 bf16 (frag-linear)
    ushort_t* xnb   = wcats + 18432;           // 8,388,608 bf16 (NHWC x)
    ushort_t* prebn = xnb + 8388608;           // 16,777,216 bf16 (NHWC pre-BN)
    float* out      = (float*)d_out;

    detect_zero<<<1, 256, 0, stream>>>((const uint4*)x, flag, gstat);
    prep_weights<<<361, 256, 0, stream>>>(offw, offb, maskw, maskb, convw, flag, wTs, wcats, bias);
    transpose_x<<<2048, 256, 0, stream>>>(x, flag, xnb);
    fused_conv_deform<<<512, 1024, 0, stream>>>(xnb, wcats, bias, wTs, prebn, gstat);
    bn_apply_t<<<2048, 256, 0, stream>>>(prebn, gstat, out);
}